// Round 9
// baseline (792.148 us; speedup 1.0000x reference)
//
#include <hip/hip_runtime.h>

#define LRELU(v) ((v) > 0.f ? (v) : 0.2f * (v))

// ---------------------------------------------------------------------------
// DPP-based full-wave (64 lane) sum.  VALU only, no DS traffic.
template <int CTRL, int RMASK>
__device__ __forceinline__ float dpp_add(float v) {
  int moved = __builtin_amdgcn_update_dpp(0, __builtin_bit_cast(int, v), CTRL,
                                          RMASK, 0xf, true);
  return v + __builtin_bit_cast(float, moved);
}
__device__ __forceinline__ float wave_sum(float v) {
  v = dpp_add<0x111, 0xf>(v);  // row_shr:1
  v = dpp_add<0x112, 0xf>(v);  // row_shr:2
  v = dpp_add<0x114, 0xf>(v);  // row_shr:4
  v = dpp_add<0x118, 0xf>(v);  // row_shr:8
  v = dpp_add<0x142, 0xa>(v);  // row_bcast:15
  v = dpp_add<0x143, 0xc>(v);  // row_bcast:31; lane63 = total
  return __builtin_bit_cast(
      float, __builtin_amdgcn_readlane(__builtin_bit_cast(int, v), 63));
}

// ---------------------------------------------------------------------------
// Both embeddings in one dispatch: lrelu(X[M,K] @ W[K,64] + b) -> out[M,64].
__global__ __launch_bounds__(256) void embed2_kernel(
    const float* __restrict__ x, const float* __restrict__ nW,
    const float* __restrict__ nb, float* __restrict__ h0, int N_,
    const float* __restrict__ eattr, const float* __restrict__ eW,
    const float* __restrict__ eb, float* __restrict__ ea, int E_,
    int nodeBlocks) {
  const int lane = threadIdx.x & 63;
  const float *X, *W, *b;
  float* out;
  int M, K, r;
  if ((int)blockIdx.x < nodeBlocks) {
    r = blockIdx.x * 4 + (threadIdx.x >> 6);
    X = x; W = nW; b = nb; out = h0; M = N_; K = 92;
  } else {
    r = (blockIdx.x - nodeBlocks) * 4 + (threadIdx.x >> 6);
    X = eattr; W = eW; b = eb; out = ea; M = E_; K = 50;
  }
  r = __builtin_amdgcn_readfirstlane(r);
  if (r >= M) return;
  float acc = b[lane];
  const float* Xr = X + (size_t)r * K;
  const float* Wl = W + lane;
  for (int k = 0; k < K; ++k) acc = fmaf(Xr[k], Wl[(size_t)k * 64], acc);
  acc = LRELU(acc);
  out[(size_t)r * 64 + lane] = acc;
}

// ---------------------------------------------------------------------------
// Fused finalize(prev layer) + P = h @ W_top  (R4-proven form).
// mode -1: A = A0 (layer 0); mode 0: h = agg*0.1+b; mode 1: h += agg*0.1+b.
__global__ __launch_bounds__(256, 4) void update_gemm_kernel(
    const float* __restrict__ A0, float* __restrict__ h,
    float* __restrict__ agg, const float* __restrict__ bvec,
    const float* __restrict__ W, float* __restrict__ P, int M, int mode) {
  const int lane = threadIdx.x & 63;
  const int wv =
      __builtin_amdgcn_readfirstlane(blockIdx.x * 4 + (threadIdx.x >> 6));
  const int r0 = wv * 4;
  if (r0 >= M) return;
  float hv[4];
  if (mode < 0) {
#pragma unroll
    for (int r = 0; r < 4; ++r) hv[r] = A0[(size_t)(r0 + r) * 64 + lane];
  } else {
    float bl = bvec[lane];
#pragma unroll
    for (int r = 0; r < 4; ++r) {
      size_t idx = (size_t)(r0 + r) * 64 + lane;
      float v = fmaf(agg[idx], 0.1f, bl);
      if (mode >= 1) v += h[idx];
      agg[idx] = 0.f;
      h[idx] = v;
      hv[r] = v;
    }
  }
  float acc[4][10];
#pragma unroll
  for (int r = 0; r < 4; ++r)
#pragma unroll
    for (int q = 0; q < 10; ++q) acc[r][q] = 0.f;
  const float* Wl = W + lane;
  float wa[10], wb[10];
#pragma unroll
  for (int q = 0; q < 10; ++q) wa[q] = Wl[q * 64];
#pragma unroll 1
  for (int k = 0; k < 64; k += 2) {
#pragma unroll
    for (int q = 0; q < 10; ++q) wb[q] = Wl[(k + 1) * 640 + q * 64];
#pragma unroll
    for (int r = 0; r < 4; ++r) {
      float a = __shfl(hv[r], k);
#pragma unroll
      for (int q = 0; q < 10; ++q) acc[r][q] = fmaf(a, wa[q], acc[r][q]);
    }
    if (k + 2 < 64) {
#pragma unroll
      for (int q = 0; q < 10; ++q) wa[q] = Wl[(k + 2) * 640 + q * 64];
    }
#pragma unroll
    for (int r = 0; r < 4; ++r) {
      float a = __shfl(hv[r], k + 1);
#pragma unroll
      for (int q = 0; q < 10; ++q) acc[r][q] = fmaf(a, wb[q], acc[r][q]);
    }
  }
#pragma unroll
  for (int r = 0; r < 4; ++r) {
    float* Crow = P + (size_t)(r0 + r) * 640;
#pragma unroll
    for (int q = 0; q < 10; ++q) Crow[q * 64 + lane] = acc[r][q];
  }
}

// ---------------------------------------------------------------------------
// Edge kernel, 2 chunks of 5 heads.  Per chunk: qacc[8][5] k-loop (W dword
// dbuf, ea via wave-uniform s_load), attention partial over 5 heads, ONLINE
// softmax merge into m[8]/mx[8]/ss[8] (R6-verified math at 5x density).
// Live set ~90 VGPR -> no allocator fission (the 80-acc version's 1.6x VALU
// stream inflation was the R4-R8 plateau).
__global__ __launch_bounds__(256, 4) void edge_fused_kernel(
    const float* __restrict__ P, const float* __restrict__ ea,
    const float* __restrict__ Wbot,  // [64, 640]
    const int* __restrict__ row, const int* __restrict__ col,
    const float* __restrict__ att, const float* __restrict__ gamma,
    const float* __restrict__ beta, float* __restrict__ agg, int E_) {
  const int lane = threadIdx.x & 63;
  const int wv =
      __builtin_amdgcn_readfirstlane(blockIdx.x * 4 + (threadIdx.x >> 6));
  const int e0 = wv * 8;
  if (e0 >= E_) return;

  int eix[8], ris[8], cis[8];  // wave-uniform -> SGPRs
#pragma unroll
  for (int r = 0; r < 8; ++r) {
    int e = (e0 + r < E_) ? (e0 + r) : (E_ - 1);
    eix[r] = e;
    ris[r] = row[e];
    cis[r] = col[e];
  }

  const float inv_std = 0.9999950000374997f;  // 1/sqrt(1+1e-5)
  float m[8];
  float mx[8], ss[8];  // uniform -> SGPRs
#pragma unroll
  for (int r = 0; r < 8; ++r) {
    m[r] = 0.f;
    mx[r] = -1e30f;
    ss[r] = 0.f;
  }

#pragma unroll 1
  for (int c = 0; c < 2; ++c) {
    // ---- Q chunk gemm: qacc[r][q] over heads c*5+q ----
    float qacc[8][5];
#pragma unroll
    for (int r = 0; r < 8; ++r)
#pragma unroll
      for (int q = 0; q < 5; ++q) qacc[r][q] = 0.f;
    const float* Wl = Wbot + c * 320 + lane;
    float wa[5], wb[5];
#pragma unroll
    for (int q = 0; q < 5; ++q) wa[q] = Wl[q * 64];
#pragma unroll 1
    for (int k = 0; k < 64; k += 2) {
#pragma unroll
      for (int q = 0; q < 5; ++q) wb[q] = Wl[(k + 1) * 640 + q * 64];
#pragma unroll
      for (int r = 0; r < 8; ++r) {
        float a = ea[(size_t)eix[r] * 64 + k];  // wave-uniform s_load
#pragma unroll
        for (int q = 0; q < 5; ++q) qacc[r][q] = fmaf(a, wa[q], qacc[r][q]);
      }
      if (k + 2 < 64) {
#pragma unroll
        for (int q = 0; q < 5; ++q) wa[q] = Wl[(k + 2) * 640 + q * 64];
      }
#pragma unroll
      for (int r = 0; r < 8; ++r) {
        float a = ea[(size_t)eix[r] * 64 + k + 1];
#pragma unroll
        for (int q = 0; q < 5; ++q) qacc[r][q] = fmaf(a, wb[q], qacc[r][q]);
      }
    }

    // ---- attention partial for heads c*5 .. c*5+4 ----
    float at_i[5], at_j[5];
    float gm[5], bt[5];  // uniform
#pragma unroll
    for (int q = 0; q < 5; ++q) {
      at_i[q] = att[(c * 5 + q) * 128 + lane];
      at_j[q] = att[(c * 5 + q) * 128 + 64 + lane];
      gm[q] = gamma[c * 5 + q];
      bt[q] = beta[c * 5 + q];
    }

    // Prefetch edge 0's P row-halves for this chunk.
    float prb[5], pcb[5];
    {
      const float* Pr = P + (size_t)ris[0] * 640 + c * 320 + lane;
      const float* Pc = P + (size_t)cis[0] * 640 + c * 320 + lane;
#pragma unroll
      for (int q = 0; q < 5; ++q) {
        prb[q] = Pr[q * 64];
        pcb[q] = Pc[q * 64];
      }
    }

#pragma unroll
    for (int r = 0; r < 8; ++r) {
      if (e0 + r >= E_) break;
      float pr[5], pc[5];
#pragma unroll
      for (int q = 0; q < 5; ++q) {
        pr[q] = prb[q];
        pc[q] = pcb[q];
      }
      if (r + 1 < 8) {  // issue next edge's gathers now
        const float* Pr = P + (size_t)ris[r + 1] * 640 + c * 320 + lane;
        const float* Pc = P + (size_t)cis[r + 1] * 640 + c * 320 + lane;
#pragma unroll
        for (int q = 0; q < 5; ++q) {
          prb[q] = Pr[q * 64];
          pcb[q] = Pc[q * 64];
        }
      }
      float hj[5], sv[5];
#pragma unroll
      for (int q = 0; q < 5; ++q) {
        float qc = qacc[r][q];
        float hi = pr[q] + qc;
        float hjv = pc[q] + qc;
        hi = LRELU(hi);
        hjv = LRELU(hjv);
        hj[q] = hjv;
        float part = fmaf(hi, at_i[q], hjv * at_j[q]);
        sv[q] = wave_sum(part);  // uniform after this
      }
      float mxc = -1e30f;
#pragma unroll
      for (int q = 0; q < 5; ++q) {
        float a = sv[q];
        a = LRELU(a);
        a = fmaf(a * inv_std, gm[q], bt[q]);
        sv[q] = a;
        mxc = fmaxf(mxc, a);
      }
      float nm = fmaxf(mx[r], mxc);
      float scale = __expf(mx[r] - nm);  // 0 on first chunk
      float sum5 = 0.f;
#pragma unroll
      for (int q = 0; q < 5; ++q) {
        float ex = __expf(sv[q] - nm);
        sv[q] = ex;
        sum5 += ex;
      }
      ss[r] = fmaf(ss[r], scale, sum5);
      float add = 0.f;
#pragma unroll
      for (int q = 0; q < 5; ++q) add = fmaf(sv[q], hj[q], add);
      m[r] = fmaf(m[r], scale, add);
      mx[r] = nm;
    }
  }

#pragma unroll
  for (int r = 0; r < 8; ++r) {
    if (e0 + r >= E_) break;
    atomicAdd(agg + (size_t)ris[r] * 64 + lane, m[r] / ss[r]);
  }
}

// ---------------------------------------------------------------------------
// Final residual: h = h + agg/NH + b + h0.  Also re-zeroes agg.
__global__ __launch_bounds__(256) void finalize_kernel(
    float* __restrict__ h, float* __restrict__ agg, const float* __restrict__ b,
    const float* __restrict__ h0, int total) {
  int idx = blockIdx.x * 256 + threadIdx.x;
  if (idx >= total) return;
  int f = idx & 63;
  float v = fmaf(agg[idx], 0.1f, b[f]);
  agg[idx] = 0.f;
  h[idx] = v + h[idx] + h0[idx];
}

// ---------------------------------------------------------------------------
// score[n] = lrelu([h[n], gf[batch[n]]] @ W1 + b1) @ W2 + b2.  Wave per node.
__global__ __launch_bounds__(256) void score_kernel(
    const float* __restrict__ h, const int* __restrict__ batch,
    const float* __restrict__ gf, const float* __restrict__ W1,
    const float* __restrict__ b1, const float* __restrict__ W2,
    const float* __restrict__ b2, float* __restrict__ score, int N_) {
  const int lane = threadIdx.x & 63;
  const int n =
      __builtin_amdgcn_readfirstlane(blockIdx.x * 4 + (threadIdx.x >> 6));
  if (n >= N_) return;
  float acc = b1[lane];
  const float* hn = h + (size_t)n * 64;  // uniform -> s_load
  const float* W1l = W1 + lane;
#pragma unroll 8
  for (int k = 0; k < 64; ++k) acc = fmaf(hn[k], W1l[k * 64], acc);
  const int bn = batch[n];  // scalar
  const float* g = gf + (size_t)bn * 108;
#pragma unroll 4
  for (int k = 0; k < 108; ++k) acc = fmaf(g[k], W1l[(64 + k) * 64], acc);
  acc = LRELU(acc);
  float v = wave_sum(acc * W2[lane]);
  if (lane == 0) score[n] = v + b2[0];
}

// ---------------------------------------------------------------------------
// Graph boundary offsets from sorted batch_idx: start[g]..start[g+1]
__global__ void bounds_kernel(const int* __restrict__ batch,
                              int* __restrict__ start, int N_, int G_) {
  int n = blockIdx.x * blockDim.x + threadIdx.x;
  if (n >= N_) return;
  int b = batch[n];
  int bp = (n == 0) ? -1 : batch[n - 1];
  for (int g = bp + 1; g <= b; ++g) start[g] = n;
  if (n == N_ - 1)
    for (int g = b + 1; g <= G_; ++g) start[g] = N_;
}

// ---------------------------------------------------------------------------
// Per-graph softmax-attention pool + output MLP.  One block per graph.
__global__ __launch_bounds__(256) void pool_out_kernel(
    const float* __restrict__ h, const float* __restrict__ score,
    const int* __restrict__ start, const float* __restrict__ W1,
    const float* __restrict__ b1, const float* __restrict__ W2,
    const float* __restrict__ b2, float* __restrict__ out) {
  int g = blockIdx.x;
  int s0 = start[g], s1 = start[g + 1];
  int tid = threadIdx.x;
  __shared__ float red[256];
  __shared__ float pool[64];
  __shared__ float sh_smax, sh_denom;
  float lm = -1e30f;
  for (int n = s0 + tid; n < s1; n += 256) lm = fmaxf(lm, score[n]);
  red[tid] = lm;
  __syncthreads();
  for (int off = 128; off; off >>= 1) {
    if (tid < off) red[tid] = fmaxf(red[tid], red[tid + off]);
    __syncthreads();
  }
  if (tid == 0) sh_smax = red[0];
  __syncthreads();
  float smax = sh_smax;
  __syncthreads();
  float ls = 0.f;
  for (int n = s0 + tid; n < s1; n += 256) ls += __expf(score[n] - smax);
  red[tid] = ls;
  __syncthreads();
  for (int off = 128; off; off >>= 1) {
    if (tid < off) red[tid] += red[tid + off];
    __syncthreads();
  }
  if (tid == 0) sh_denom = red[0];
  __syncthreads();
  float denom = sh_denom;
  float invd = denom > 0.f ? 1.0f / denom : 0.f;
  __syncthreads();
  int f = tid & 63, sub = tid >> 6;
  float acc = 0.f;
  for (int n = s0 + sub; n < s1; n += 4)
    acc = fmaf(__expf(score[n] - smax), h[(size_t)n * 64 + f], acc);
  red[tid] = acc;
  __syncthreads();
  if (tid < 64)
    pool[tid] =
        (red[tid] + red[tid + 64] + red[tid + 128] + red[tid + 192]) * invd;
  __syncthreads();
  if (tid < 64) {
    float a = b1[tid];
#pragma unroll 8
    for (int k = 0; k < 64; ++k) a = fmaf(pool[k], W1[k * 64 + tid], a);
    a = fmaxf(a, 0.f);
    red[tid] = a * W2[tid];
  }
  __syncthreads();
  if (tid == 0) {
    float s = 0.f;
    for (int k = 0; k < 64; ++k) s += red[k];
    out[g] = s + b2[0];
  }
}

// ---------------------------------------------------------------------------
extern "C" void kernel_launch(void* const* d_in, const int* in_sizes, int n_in,
                              void* d_out, int out_size, void* d_ws,
                              size_t ws_size, hipStream_t stream) {
  const float* x          = (const float*)d_in[0];
  const int*   edge_index = (const int*)d_in[1];
  const float* edge_attr  = (const float*)d_in[2];
  const int*   batch_idx  = (const int*)d_in[3];
  const float* gf         = (const float*)d_in[4];
  const float* node_W     = (const float*)d_in[5];
  const float* node_b     = (const float*)d_in[6];
  const float* edge_W     = (const float*)d_in[7];
  const float* edge_b     = (const float*)d_in[8];
  const float* conv_W     = (const float*)d_in[9];
  const float* conv_att   = (const float*)d_in[10];
  const float* conv_b     = (const float*)d_in[11];
  const float* conv_gamma = (const float*)d_in[12];
  const float* conv_beta  = (const float*)d_in[13];
  const float* ga_W1      = (const float*)d_in[14];
  const float* ga_b1      = (const float*)d_in[15];
  const float* ga_W2      = (const float*)d_in[16];
  const float* ga_b2      = (const float*)d_in[17];
  const float* out_W1     = (const float*)d_in[18];
  const float* out_b1     = (const float*)d_in[19];
  const float* out_W2     = (const float*)d_in[20];
  const float* out_b2     = (const float*)d_in[21];
  float* out = (float*)d_out;

  const int N = in_sizes[3];        // 10000
  const int E = in_sizes[2] / 50;   // 40000
  const int G = in_sizes[4] / 108;  // 128
  const int L = 5;

  float* ws = (float*)d_ws;
  float* h    = ws;  ws += (size_t)N * 64;
  float* h0   = ws;  ws += (size_t)N * 64;
  float* ea   = ws;  ws += (size_t)E * 64;
  float* P    = ws;  ws += (size_t)N * 640;
  float* agg  = ws;  ws += (size_t)N * 64;
  float* scr  = ws;  ws += N;
  int* gstart = (int*)ws;

  const int* row = edge_index;
  const int* col = edge_index + E;

  int nodeBlocks = (N + 3) / 4;
  int edgeBlocks = (E + 3) / 4;
  embed2_kernel<<<nodeBlocks + edgeBlocks, 256, 0, stream>>>(
      x, node_W, node_b, h0, N, edge_attr, edge_W, edge_b, ea, E, nodeBlocks);
  (void)hipMemsetAsync(agg, 0, (size_t)N * 64 * sizeof(float), stream);

  for (int i = 0; i < L; ++i) {
    const float* Wi = conv_W + (size_t)i * 128 * 640;
    if (i == 0) {
      update_gemm_kernel<<<(N / 4 + 3) / 4, 256, 0, stream>>>(
          h0, h, agg, nullptr, Wi, P, N, -1);
    } else {
      update_gemm_kernel<<<(N / 4 + 3) / 4, 256, 0, stream>>>(
          nullptr, h, agg, conv_b + (i - 1) * 64, Wi, P, N,
          (i - 1) == 0 ? 0 : 1);
    }
    int waves = (E + 7) / 8;
    edge_fused_kernel<<<(waves + 3) / 4, 256, 0, stream>>>(
        P, ea, Wi + 64 * 640, row, col, conv_att + (size_t)i * 1280,
        conv_gamma + i * 10, conv_beta + i * 10, agg, E);
  }
  finalize_kernel<<<(N * 64 + 255) / 256, 256, 0, stream>>>(
      h, agg, conv_b + (L - 1) * 64, h0, N * 64);

  score_kernel<<<(N + 3) / 4, 256, 0, stream>>>(h, batch_idx, gf, ga_W1, ga_b1,
                                                ga_W2, ga_b2, scr, N);
  bounds_kernel<<<(N + 255) / 256, 256, 0, stream>>>(batch_idx, gstart, N, G);
  pool_out_kernel<<<G, 256, 0, stream>>>(h, scr, gstart, out_W1, out_b1, out_W2,
                                         out_b2, out);
}

// Round 12
// 750.948 us; speedup vs baseline: 1.0549x; 1.0549x over previous
//
#include <hip/hip_runtime.h>

#define LRELU(v) ((v) > 0.f ? (v) : 0.2f * (v))

// ---------------------------------------------------------------------------
// DPP-based full-wave (64 lane) sum.  VALU only, no DS traffic.
template <int CTRL, int RMASK>
__device__ __forceinline__ float dpp_add(float v) {
  int moved = __builtin_amdgcn_update_dpp(0, __builtin_bit_cast(int, v), CTRL,
                                          RMASK, 0xf, true);
  return v + __builtin_bit_cast(float, moved);
}
__device__ __forceinline__ float wave_sum(float v) {
  v = dpp_add<0x111, 0xf>(v);  // row_shr:1
  v = dpp_add<0x112, 0xf>(v);  // row_shr:2
  v = dpp_add<0x114, 0xf>(v);  // row_shr:4
  v = dpp_add<0x118, 0xf>(v);  // row_shr:8
  v = dpp_add<0x142, 0xa>(v);  // row_bcast:15
  v = dpp_add<0x143, 0xc>(v);  // row_bcast:31; lane63 = total
  return __builtin_bit_cast(
      float, __builtin_amdgcn_readlane(__builtin_bit_cast(int, v), 63));
}

// ---------------------------------------------------------------------------
// Both embeddings in one dispatch: lrelu(X[M,K] @ W[K,64] + b) -> out[M,64].
__global__ __launch_bounds__(256) void embed2_kernel(
    const float* __restrict__ x, const float* __restrict__ nW,
    const float* __restrict__ nb, float* __restrict__ h0, int N_,
    const float* __restrict__ eattr, const float* __restrict__ eW,
    const float* __restrict__ eb, float* __restrict__ ea, int E_,
    int nodeBlocks) {
  const int lane = threadIdx.x & 63;
  const float *X, *W, *b;
  float* out;
  int M, K, r;
  if ((int)blockIdx.x < nodeBlocks) {
    r = blockIdx.x * 4 + (threadIdx.x >> 6);
    X = x; W = nW; b = nb; out = h0; M = N_; K = 92;
  } else {
    r = (blockIdx.x - nodeBlocks) * 4 + (threadIdx.x >> 6);
    X = eattr; W = eW; b = eb; out = ea; M = E_; K = 50;
  }
  r = __builtin_amdgcn_readfirstlane(r);
  if (r >= M) return;
  float acc = b[lane];
  const float* Xr = X + (size_t)r * K;
  const float* Wl = W + lane;
  for (int k = 0; k < K; ++k) acc = fmaf(Xr[k], Wl[(size_t)k * 64], acc);
  acc = LRELU(acc);
  out[(size_t)r * 64 + lane] = acc;
}

// ---------------------------------------------------------------------------
// Fused finalize(prev layer) + P = h @ W_top  (R4-proven form).
// mode -1: A = A0 (layer 0); mode 0: h = agg*0.1+b; mode 1: h += agg*0.1+b.
__global__ __launch_bounds__(256, 4) void update_gemm_kernel(
    const float* __restrict__ A0, float* __restrict__ h,
    float* __restrict__ agg, const float* __restrict__ bvec,
    const float* __restrict__ W, float* __restrict__ P, int M, int mode) {
  const int lane = threadIdx.x & 63;
  const int wv =
      __builtin_amdgcn_readfirstlane(blockIdx.x * 4 + (threadIdx.x >> 6));
  const int r0 = wv * 4;
  if (r0 >= M) return;
  float hv[4];
  if (mode < 0) {
#pragma unroll
    for (int r = 0; r < 4; ++r) hv[r] = A0[(size_t)(r0 + r) * 64 + lane];
  } else {
    float bl = bvec[lane];
#pragma unroll
    for (int r = 0; r < 4; ++r) {
      size_t idx = (size_t)(r0 + r) * 64 + lane;
      float v = fmaf(agg[idx], 0.1f, bl);
      if (mode >= 1) v += h[idx];
      agg[idx] = 0.f;
      h[idx] = v;
      hv[r] = v;
    }
  }
  float acc[4][10];
#pragma unroll
  for (int r = 0; r < 4; ++r)
#pragma unroll
    for (int q = 0; q < 10; ++q) acc[r][q] = 0.f;
  const float* Wl = W + lane;
  float wa[10], wb[10];
#pragma unroll
  for (int q = 0; q < 10; ++q) wa[q] = Wl[q * 64];
#pragma unroll 1
  for (int k = 0; k < 64; k += 2) {
#pragma unroll
    for (int q = 0; q < 10; ++q) wb[q] = Wl[(k + 1) * 640 + q * 64];
#pragma unroll
    for (int r = 0; r < 4; ++r) {
      float a = __shfl(hv[r], k);
#pragma unroll
      for (int q = 0; q < 10; ++q) acc[r][q] = fmaf(a, wa[q], acc[r][q]);
    }
    if (k + 2 < 64) {
#pragma unroll
      for (int q = 0; q < 10; ++q) wa[q] = Wl[(k + 2) * 640 + q * 64];
    }
#pragma unroll
    for (int r = 0; r < 4; ++r) {
      float a = __shfl(hv[r], k + 1);
#pragma unroll
      for (int q = 0; q < 10; ++q) acc[r][q] = fmaf(a, wb[q], acc[r][q]);
    }
  }
#pragma unroll
  for (int r = 0; r < 4; ++r) {
    float* Crow = P + (size_t)(r0 + r) * 640;
#pragma unroll
    for (int q = 0; q < 10; ++q) Crow[q * 64 + lane] = acc[r][q];
  }
}

// ---------------------------------------------------------------------------
// Edge kernel, WAVE-PAIR head split.  A pair (w0,w1) co-owns 8 edges:
// w0 computes heads 0-4, w1 heads 5-9.  Each wave: qacc[8][5] = 40 accs
// (fits arch VGPRs -> no accvgpr read/write tax), full 8-edge FMA density,
// P gathers on disjoint column halves.  Logits (wave-uniform after DPP
// reduce) exchanged via LDS (barrier 1); both waves compute the 10-head
// softmax; w1 passes its partial message via LDS (barrier 2); w0 atomics.
// All waves reach both barriers unconditionally (guards only on stores).
__global__ __launch_bounds__(256, 4) void edge_fused_kernel(
    const float* __restrict__ P, const float* __restrict__ ea,
    const float* __restrict__ Wbot,  // [64, 640]
    const int* __restrict__ row, const int* __restrict__ col,
    const float* __restrict__ att, const float* __restrict__ gamma,
    const float* __restrict__ beta, float* __restrict__ agg, int E_) {
  __shared__ float lg[2][8][10];  // normalized logits [pair][edge][head]
  __shared__ float mb[2][8][64];  // w1 partial messages [pair][edge][lane]
  const int tid = threadIdx.x;
  const int lane = tid & 63;
  const int wid = tid >> 6;  // 0..3
  const int pairi = wid >> 1, half = wid & 1;
  const int pidx = __builtin_amdgcn_readfirstlane(blockIdx.x * 2 + pairi);
  const int e0 = pidx * 8;
  const bool active = e0 < E_;
  const int e0c = active ? e0 : 0;

  int eix[8], ris[8], cis[8];  // wave-uniform -> SGPRs
#pragma unroll
  for (int r = 0; r < 8; ++r) {
    int e = (e0c + r < E_) ? (e0c + r) : (E_ - 1);
    eix[r] = e;
    ris[r] = row[e];
    cis[r] = col[e];
  }

  // ---- Q-gemm for this wave's 5 heads: qacc[8][5] ----
  float qacc[8][5];
#pragma unroll
  for (int r = 0; r < 8; ++r)
#pragma unroll
    for (int q = 0; q < 5; ++q) qacc[r][q] = 0.f;
  {
    const float* Wl = Wbot + half * 320 + lane;
    float wa[5], wb[5];
#pragma unroll
    for (int q = 0; q < 5; ++q) wa[q] = Wl[q * 64];
#pragma unroll 1
    for (int k = 0; k < 64; k += 2) {
#pragma unroll
      for (int q = 0; q < 5; ++q) wb[q] = Wl[(k + 1) * 640 + q * 64];
#pragma unroll
      for (int r = 0; r < 8; ++r) {
        float a = ea[(size_t)eix[r] * 64 + k];  // wave-uniform s_load
#pragma unroll
        for (int q = 0; q < 5; ++q) qacc[r][q] = fmaf(a, wa[q], qacc[r][q]);
      }
      if (k + 2 < 64) {
#pragma unroll
        for (int q = 0; q < 5; ++q) wa[q] = Wl[(k + 2) * 640 + q * 64];
      }
#pragma unroll
      for (int r = 0; r < 8; ++r) {
        float a = ea[(size_t)eix[r] * 64 + k + 1];
#pragma unroll
        for (int q = 0; q < 5; ++q) qacc[r][q] = fmaf(a, wb[q], qacc[r][q]);
      }
    }
  }

  // ---- phase 1: logits for my 5 heads (normalized), hj kept in regs ----
  const float inv_std = 0.9999950000374997f;  // 1/sqrt(1+1e-5)
  float at_i[5], at_j[5];
  float gm[5], bt[5];  // uniform
#pragma unroll
  for (int q = 0; q < 5; ++q) {
    at_i[q] = att[(half * 5 + q) * 128 + lane];
    at_j[q] = att[(half * 5 + q) * 128 + 64 + lane];
    gm[q] = gamma[half * 5 + q];
    bt[q] = beta[half * 5 + q];
  }

  float prb[5], pcb[5];  // prefetch dbuf (column half = half*320)
  {
    const float* Pr = P + (size_t)ris[0] * 640 + half * 320 + lane;
    const float* Pc = P + (size_t)cis[0] * 640 + half * 320 + lane;
#pragma unroll
    for (int q = 0; q < 5; ++q) {
      prb[q] = Pr[q * 64];
      pcb[q] = Pc[q * 64];
    }
  }

  float hj[8][5];
#pragma unroll
  for (int r = 0; r < 8; ++r) {
    float pr[5], pc[5];
#pragma unroll
    for (int q = 0; q < 5; ++q) {
      pr[q] = prb[q];
      pc[q] = pcb[q];
    }
    if (r + 1 < 8) {
      const float* Pr = P + (size_t)ris[r + 1] * 640 + half * 320 + lane;
      const float* Pc = P + (size_t)cis[r + 1] * 640 + half * 320 + lane;
#pragma unroll
      for (int q = 0; q < 5; ++q) {
        prb[q] = Pr[q * 64];
        pcb[q] = Pc[q * 64];
      }
    }
    float lq[5];
#pragma unroll
    for (int q = 0; q < 5; ++q) {
      float qc = qacc[r][q];
      float hi = pr[q] + qc;
      float hjv = pc[q] + qc;
      hi = LRELU(hi);
      hjv = LRELU(hjv);
      hj[r][q] = hjv;
      float part = fmaf(hi, at_i[q], hjv * at_j[q]);
      float s = wave_sum(part);  // uniform
      float a = LRELU(s);
      lq[q] = fmaf(a * inv_std, gm[q], bt[q]);
    }
    if (lane == 0) {
#pragma unroll
      for (int q = 0; q < 5; ++q) lg[pairi][r][half * 5 + q] = lq[q];
    }
  }
  __syncthreads();  // logits of both halves visible

  // ---- phase 2: full softmax (redundant in both waves), partial message ----
  float m[8];
#pragma unroll
  for (int r = 0; r < 8; ++r) {
    float v[10];
#pragma unroll
    for (int j = 0; j < 10; ++j) v[j] = lg[pairi][r][j];
    float mx = -1e30f;
#pragma unroll
    for (int j = 0; j < 10; ++j) mx = fmaxf(mx, v[j]);
    float ssum = 0.f;
    float ex5[5];
#pragma unroll
    for (int j = 0; j < 10; ++j) {
      float ex = __expf(v[j] - mx);
      ssum += ex;
      int q = j - half * 5;
      if (q >= 0 && q < 5) ex5[q] = ex;
    }
    float inv = 1.0f / ssum;
    float acc = 0.f;
#pragma unroll
    for (int q = 0; q < 5; ++q) acc = fmaf(ex5[q] * inv, hj[r][q], acc);
    m[r] = acc;
    if (half == 1) mb[pairi][r][lane] = acc;
  }
  __syncthreads();  // w1 partials visible

  if (active && half == 0) {
#pragma unroll
    for (int r = 0; r < 8; ++r) {
      if (e0 + r >= E_) break;
      atomicAdd(agg + (size_t)ris[r] * 64 + lane, m[r] + mb[pairi][r][lane]);
    }
  }
}

// ---------------------------------------------------------------------------
// Final residual: h = h + agg/NH + b + h0.  Also re-zeroes agg.
__global__ __launch_bounds__(256) void finalize_kernel(
    float* __restrict__ h, float* __restrict__ agg, const float* __restrict__ b,
    const float* __restrict__ h0, int total) {
  int idx = blockIdx.x * 256 + threadIdx.x;
  if (idx >= total) return;
  int f = idx & 63;
  float v = fmaf(agg[idx], 0.1f, b[f]);
  agg[idx] = 0.f;
  h[idx] = v + h[idx] + h0[idx];
}

// ---------------------------------------------------------------------------
// score[n] = lrelu([h[n], gf[batch[n]]] @ W1 + b1) @ W2 + b2.  Wave per node.
__global__ __launch_bounds__(256) void score_kernel(
    const float* __restrict__ h, const int* __restrict__ batch,
    const float* __restrict__ gf, const float* __restrict__ W1,
    const float* __restrict__ b1, const float* __restrict__ W2,
    const float* __restrict__ b2, float* __restrict__ score, int N_) {
  const int lane = threadIdx.x & 63;
  const int n =
      __builtin_amdgcn_readfirstlane(blockIdx.x * 4 + (threadIdx.x >> 6));
  if (n >= N_) return;
  float acc = b1[lane];
  const float* hn = h + (size_t)n * 64;  // uniform -> s_load
  const float* W1l = W1 + lane;
#pragma unroll 8
  for (int k = 0; k < 64; ++k) acc = fmaf(hn[k], W1l[k * 64], acc);
  const int bn = batch[n];  // scalar
  const float* g = gf + (size_t)bn * 108;
#pragma unroll 4
  for (int k = 0; k < 108; ++k) acc = fmaf(g[k], W1l[(64 + k) * 64], acc);
  acc = LRELU(acc);
  float v = wave_sum(acc * W2[lane]);
  if (lane == 0) score[n] = v + b2[0];
}

// ---------------------------------------------------------------------------
// Graph boundary offsets from sorted batch_idx: start[g]..start[g+1]
__global__ void bounds_kernel(const int* __restrict__ batch,
                              int* __restrict__ start, int N_, int G_) {
  int n = blockIdx.x * blockDim.x + threadIdx.x;
  if (n >= N_) return;
  int b = batch[n];
  int bp = (n == 0) ? -1 : batch[n - 1];
  for (int g = bp + 1; g <= b; ++g) start[g] = n;
  if (n == N_ - 1)
    for (int g = b + 1; g <= G_; ++g) start[g] = N_;
}

// ---------------------------------------------------------------------------
// Per-graph softmax-attention pool + output MLP.  One block per graph.
__global__ __launch_bounds__(256) void pool_out_kernel(
    const float* __restrict__ h, const float* __restrict__ score,
    const int* __restrict__ start, const float* __restrict__ W1,
    const float* __restrict__ b1, const float* __restrict__ W2,
    const float* __restrict__ b2, float* __restrict__ out) {
  int g = blockIdx.x;
  int s0 = start[g], s1 = start[g + 1];
  int tid = threadIdx.x;
  __shared__ float red[256];
  __shared__ float pool[64];
  __shared__ float sh_smax, sh_denom;
  float lm = -1e30f;
  for (int n = s0 + tid; n < s1; n += 256) lm = fmaxf(lm, score[n]);
  red[tid] = lm;
  __syncthreads();
  for (int off = 128; off; off >>= 1) {
    if (tid < off) red[tid] = fmaxf(red[tid], red[tid + off]);
    __syncthreads();
  }
  if (tid == 0) sh_smax = red[0];
  __syncthreads();
  float smax = sh_smax;
  __syncthreads();
  float ls = 0.f;
  for (int n = s0 + tid; n < s1; n += 256) ls += __expf(score[n] - smax);
  red[tid] = ls;
  __syncthreads();
  for (int off = 128; off; off >>= 1) {
    if (tid < off) red[tid] += red[tid + off];
    __syncthreads();
  }
  if (tid == 0) sh_denom = red[0];
  __syncthreads();
  float denom = sh_denom;
  float invd = denom > 0.f ? 1.0f / denom : 0.f;
  __syncthreads();
  int f = tid & 63, sub = tid >> 6;
  float acc = 0.f;
  for (int n = s0 + sub; n < s1; n += 4)
    acc = fmaf(__expf(score[n] - smax), h[(size_t)n * 64 + f], acc);
  red[tid] = acc;
  __syncthreads();
  if (tid < 64)
    pool[tid] =
        (red[tid] + red[tid + 64] + red[tid + 128] + red[tid + 192]) * invd;
  __syncthreads();
  if (tid < 64) {
    float a = b1[tid];
#pragma unroll 8
    for (int k = 0; k < 64; ++k) a = fmaf(pool[k], W1[k * 64 + tid], a);
    a = fmaxf(a, 0.f);
    red[tid] = a * W2[tid];
  }
  __syncthreads();
  if (tid == 0) {
    float s = 0.f;
    for (int k = 0; k < 64; ++k) s += red[k];
    out[g] = s + b2[0];
  }
}

// ---------------------------------------------------------------------------
extern "C" void kernel_launch(void* const* d_in, const int* in_sizes, int n_in,
                              void* d_out, int out_size, void* d_ws,
                              size_t ws_size, hipStream_t stream) {
  const float* x          = (const float*)d_in[0];
  const int*   edge_index = (const int*)d_in[1];
  const float* edge_attr  = (const float*)d_in[2];
  const int*   batch_idx  = (const int*)d_in[3];
  const float* gf         = (const float*)d_in[4];
  const float* node_W     = (const float*)d_in[5];
  const float* node_b     = (const float*)d_in[6];
  const float* edge_W     = (const float*)d_in[7];
  const float* edge_b     = (const float*)d_in[8];
  const float* conv_W     = (const float*)d_in[9];
  const float* conv_att   = (const float*)d_in[10];
  const float* conv_b     = (const float*)d_in[11];
  const float* conv_gamma = (const float*)d_in[12];
  const float* conv_beta  = (const float*)d_in[13];
  const float* ga_W1      = (const float*)d_in[14];
  const float* ga_b1      = (const float*)d_in[15];
  const float* ga_W2      = (const float*)d_in[16];
  const float* ga_b2      = (const float*)d_in[17];
  const float* out_W1     = (const float*)d_in[18];
  const float* out_b1     = (const float*)d_in[19];
  const float* out_W2     = (const float*)d_in[20];
  const float* out_b2     = (const float*)d_in[21];
  float* out = (float*)d_out;

  const int N = in_sizes[3];        // 10000
  const int E = in_sizes[2] / 50;   // 40000
  const int G = in_sizes[4] / 108;  // 128
  const int L = 5;

  float* ws = (float*)d_ws;
  float* h    = ws;  ws += (size_t)N * 64;
  float* h0   = ws;  ws += (size_t)N * 64;
  float* ea   = ws;  ws += (size_t)E * 64;
  float* P    = ws;  ws += (size_t)N * 640;
  float* agg  = ws;  ws += (size_t)N * 64;
  float* scr  = ws;  ws += N;
  int* gstart = (int*)ws;

  const int* row = edge_index;
  const int* col = edge_index + E;

  int nodeBlocks = (N + 3) / 4;
  int edgeBlocks = (E + 3) / 4;
  embed2_kernel<<<nodeBlocks + edgeBlocks, 256, 0, stream>>>(
      x, node_W, node_b, h0, N, edge_attr, edge_W, edge_b, ea, E, nodeBlocks);
  (void)hipMemsetAsync(agg, 0, (size_t)N * 64 * sizeof(float), stream);

  for (int i = 0; i < L; ++i) {
    const float* Wi = conv_W + (size_t)i * 128 * 640;
    if (i == 0) {
      update_gemm_kernel<<<(N / 4 + 3) / 4, 256, 0, stream>>>(
          h0, h, agg, nullptr, Wi, P, N, -1);
    } else {
      update_gemm_kernel<<<(N / 4 + 3) / 4, 256, 0, stream>>>(
          nullptr, h, agg, conv_b + (i - 1) * 64, Wi, P, N,
          (i - 1) == 0 ? 0 : 1);
    }
    int pairs = (E + 7) / 8;
    edge_fused_kernel<<<(pairs + 1) / 2, 256, 0, stream>>>(
        P, ea, Wi + 64 * 640, row, col, conv_att + (size_t)i * 1280,
        conv_gamma + i * 10, conv_beta + i * 10, agg, E);
  }
  finalize_kernel<<<(N * 64 + 255) / 256, 256, 0, stream>>>(
      h, agg, conv_b + (L - 1) * 64, h0, N * 64);

  score_kernel<<<(N + 3) / 4, 256, 0, stream>>>(h, batch_idx, gf, ga_W1, ga_b1,
                                                ga_W2, ga_b2, scr, N);
  bounds_kernel<<<(N + 255) / 256, 256, 0, stream>>>(batch_idx, gstart, N, G);
  pool_out_kernel<<<G, 256, 0, stream>>>(h, scr, gstart, out_W1, out_b1, out_W2,
                                         out_b2, out);
}

// Round 13
// 683.533 us; speedup vs baseline: 1.1589x; 1.0986x over previous
//
#include <hip/hip_runtime.h>

#define LRELU(v) ((v) > 0.f ? (v) : 0.2f * (v))

// ---------------------------------------------------------------------------
// DPP-based full-wave (64 lane) sum.  VALU only, no DS traffic.
template <int CTRL, int RMASK>
__device__ __forceinline__ float dpp_add(float v) {
  int moved = __builtin_amdgcn_update_dpp(0, __builtin_bit_cast(int, v), CTRL,
                                          RMASK, 0xf, true);
  return v + __builtin_bit_cast(float, moved);
}
__device__ __forceinline__ float wave_sum(float v) {
  v = dpp_add<0x111, 0xf>(v);  // row_shr:1
  v = dpp_add<0x112, 0xf>(v);  // row_shr:2
  v = dpp_add<0x114, 0xf>(v);  // row_shr:4
  v = dpp_add<0x118, 0xf>(v);  // row_shr:8
  v = dpp_add<0x142, 0xa>(v);  // row_bcast:15
  v = dpp_add<0x143, 0xc>(v);  // row_bcast:31; lane63 = total
  return __builtin_bit_cast(
      float, __builtin_amdgcn_readlane(__builtin_bit_cast(int, v), 63));
}

// ---------------------------------------------------------------------------
// Both embeddings in one dispatch: lrelu(X[M,K] @ W[K,64] + b) -> out[M,64].
__global__ __launch_bounds__(256) void embed2_kernel(
    const float* __restrict__ x, const float* __restrict__ nW,
    const float* __restrict__ nb, float* __restrict__ h0, int N_,
    const float* __restrict__ eattr, const float* __restrict__ eW,
    const float* __restrict__ eb, float* __restrict__ ea, int E_,
    int nodeBlocks) {
  const int lane = threadIdx.x & 63;
  const float *X, *W, *b;
  float* out;
  int M, K, r;
  if ((int)blockIdx.x < nodeBlocks) {
    r = blockIdx.x * 4 + (threadIdx.x >> 6);
    X = x; W = nW; b = nb; out = h0; M = N_; K = 92;
  } else {
    r = (blockIdx.x - nodeBlocks) * 4 + (threadIdx.x >> 6);
    X = eattr; W = eW; b = eb; out = ea; M = E_; K = 50;
  }
  r = __builtin_amdgcn_readfirstlane(r);
  if (r >= M) return;
  float acc = b[lane];
  const float* Xr = X + (size_t)r * K;
  const float* Wl = W + lane;
  for (int k = 0; k < K; ++k) acc = fmaf(Xr[k], Wl[(size_t)k * 64], acc);
  acc = LRELU(acc);
  out[(size_t)r * 64 + lane] = acc;
}

// ---------------------------------------------------------------------------
// Fused finalize(prev layer) + P = h @ W_top  (R4-proven form).
// mode -1: A = A0 (layer 0); mode 0: h = agg*0.1+b; mode 1: h += agg*0.1+b.
__global__ __launch_bounds__(256, 4) void update_gemm_kernel(
    const float* __restrict__ A0, float* __restrict__ h,
    float* __restrict__ agg, const float* __restrict__ bvec,
    const float* __restrict__ W, float* __restrict__ P, int M, int mode) {
  const int lane = threadIdx.x & 63;
  const int wv =
      __builtin_amdgcn_readfirstlane(blockIdx.x * 4 + (threadIdx.x >> 6));
  const int r0 = wv * 4;
  if (r0 >= M) return;
  float hv[4];
  if (mode < 0) {
#pragma unroll
    for (int r = 0; r < 4; ++r) hv[r] = A0[(size_t)(r0 + r) * 64 + lane];
  } else {
    float bl = bvec[lane];
#pragma unroll
    for (int r = 0; r < 4; ++r) {
      size_t idx = (size_t)(r0 + r) * 64 + lane;
      float v = fmaf(agg[idx], 0.1f, bl);
      if (mode >= 1) v += h[idx];
      agg[idx] = 0.f;
      h[idx] = v;
      hv[r] = v;
    }
  }
  float acc[4][10];
#pragma unroll
  for (int r = 0; r < 4; ++r)
#pragma unroll
    for (int q = 0; q < 10; ++q) acc[r][q] = 0.f;
  const float* Wl = W + lane;
  float wa[10], wb[10];
#pragma unroll
  for (int q = 0; q < 10; ++q) wa[q] = Wl[q * 64];
#pragma unroll 1
  for (int k = 0; k < 64; k += 2) {
#pragma unroll
    for (int q = 0; q < 10; ++q) wb[q] = Wl[(k + 1) * 640 + q * 64];
#pragma unroll
    for (int r = 0; r < 4; ++r) {
      float a = __shfl(hv[r], k);
#pragma unroll
      for (int q = 0; q < 10; ++q) acc[r][q] = fmaf(a, wa[q], acc[r][q]);
    }
    if (k + 2 < 64) {
#pragma unroll
      for (int q = 0; q < 10; ++q) wa[q] = Wl[(k + 2) * 640 + q * 64];
    }
#pragma unroll
    for (int r = 0; r < 4; ++r) {
      float a = __shfl(hv[r], k + 1);
#pragma unroll
      for (int q = 0; q < 10; ++q) acc[r][q] = fmaf(a, wb[q], acc[r][q]);
    }
  }
#pragma unroll
  for (int r = 0; r < 4; ++r) {
    float* Crow = P + (size_t)(r0 + r) * 640;
#pragma unroll
    for (int q = 0; q < 10; ++q) Crow[q * 64 + lane] = acc[r][q];
  }
}

// ---------------------------------------------------------------------------
// R4-proven edge kernel: 8 edges/wave, qacc[8][10], W dword double-buffer,
// ea via wave-uniform s_load, P prefetch dbuf, DPP wave_sum, one atomic/edge.
// launch_bounds(256,4): VGPR use ~64 < 128 cap; allows 4 blocks/CU.
__global__ __launch_bounds__(256, 4) void edge_fused_kernel(
    const float* __restrict__ P, const float* __restrict__ ea,
    const float* __restrict__ Wbot,  // [64, 640]
    const int* __restrict__ row, const int* __restrict__ col,
    const float* __restrict__ att, const float* __restrict__ gamma,
    const float* __restrict__ beta, float* __restrict__ agg, int E_) {
  const int lane = threadIdx.x & 63;
  const int wv =
      __builtin_amdgcn_readfirstlane(blockIdx.x * 4 + (threadIdx.x >> 6));
  const int e0 = wv * 8;
  if (e0 >= E_) return;

  int eix[8], ris[8], cis[8];  // wave-uniform -> SGPRs
#pragma unroll
  for (int r = 0; r < 8; ++r) {
    int e = (e0 + r < E_) ? (e0 + r) : (E_ - 1);
    eix[r] = e;
    ris[r] = row[e];
    cis[r] = col[e];
  }

  float qacc[8][10];
#pragma unroll
  for (int r = 0; r < 8; ++r)
#pragma unroll
    for (int q = 0; q < 10; ++q) qacc[r][q] = 0.f;

  const float* Wl = Wbot + lane;
  float wa[10], wb[10];
#pragma unroll
  for (int q = 0; q < 10; ++q) wa[q] = Wl[q * 64];
#pragma unroll 1
  for (int k = 0; k < 64; k += 2) {
#pragma unroll
    for (int q = 0; q < 10; ++q) wb[q] = Wl[(k + 1) * 640 + q * 64];
#pragma unroll
    for (int r = 0; r < 8; ++r) {
      float a = ea[(size_t)eix[r] * 64 + k];  // wave-uniform s_load
#pragma unroll
      for (int q = 0; q < 10; ++q) qacc[r][q] = fmaf(a, wa[q], qacc[r][q]);
    }
    if (k + 2 < 64) {
#pragma unroll
      for (int q = 0; q < 10; ++q) wa[q] = Wl[(k + 2) * 640 + q * 64];
    }
#pragma unroll
    for (int r = 0; r < 8; ++r) {
      float a = ea[(size_t)eix[r] * 64 + k + 1];
#pragma unroll
      for (int q = 0; q < 10; ++q) qacc[r][q] = fmaf(a, wb[q], qacc[r][q]);
    }
  }

  const float inv_std = 0.9999950000374997f;  // 1/sqrt(1+1e-5)
  float gm[10], bt[10];  // wave-uniform -> SGPRs
#pragma unroll
  for (int q = 0; q < 10; ++q) {
    gm[q] = gamma[q];
    bt[q] = beta[q];
  }

  // Prefetch edge 0's P rows.
  float prb[10], pcb[10];
  {
    const float* Pr = P + (size_t)ris[0] * 640 + lane;
    const float* Pc = P + (size_t)cis[0] * 640 + lane;
#pragma unroll
    for (int q = 0; q < 10; ++q) {
      prb[q] = Pr[q * 64];
      pcb[q] = Pc[q * 64];
    }
  }

#pragma unroll
  for (int r = 0; r < 8; ++r) {
    if (e0 + r >= E_) break;
    float pr[10], pc[10];
#pragma unroll
    for (int q = 0; q < 10; ++q) {
      pr[q] = prb[q];
      pc[q] = pcb[q];
    }
    if (r + 1 < 8) {  // issue next edge's gathers now
      const float* Pr = P + (size_t)ris[r + 1] * 640 + lane;
      const float* Pc = P + (size_t)cis[r + 1] * 640 + lane;
#pragma unroll
      for (int q = 0; q < 10; ++q) {
        prb[q] = Pr[q * 64];
        pcb[q] = Pc[q * 64];
      }
    }
    float hj[10], sv[10];
#pragma unroll
    for (int q = 0; q < 10; ++q) {
      float qc = qacc[r][q];
      float hi = pr[q] + qc;
      float hjv = pc[q] + qc;
      hi = LRELU(hi);
      hjv = LRELU(hjv);
      hj[q] = hjv;
      float part =
          fmaf(hi, att[q * 128 + lane], hjv * att[q * 128 + 64 + lane]);
      sv[q] = wave_sum(part);  // uniform after this
    }
    float mx = -1e30f;
#pragma unroll
    for (int q = 0; q < 10; ++q) {
      float a = sv[q];
      a = LRELU(a);
      a = fmaf(a * inv_std, gm[q], bt[q]);
      sv[q] = a;
      mx = fmaxf(mx, a);
    }
    float ssum = 0.f;
#pragma unroll
    for (int q = 0; q < 10; ++q) {
      float ex = __expf(sv[q] - mx);
      sv[q] = ex;
      ssum += ex;
    }
    float inv = 1.0f / ssum;
    float m = 0.f;
#pragma unroll
    for (int q = 0; q < 10; ++q) m = fmaf(sv[q] * inv, hj[q], m);
    atomicAdd(agg + (size_t)ris[r] * 64 + lane, m);
  }
}

// ---------------------------------------------------------------------------
// Fused final-residual + attention score.  Per node n:
//   hv = h[n] + agg[n]*0.1 + cb + h0[n]   (lane-parallel, coalesced)
//   h[n] = hv                             (pool_out reads it later)
//   score[n] = lrelu([hv, gf[batch[n]]] @ W1 + b1) @ W2 + b2
// hv broadcast per-k via __shfl (proven pattern from update_gemm).
__global__ __launch_bounds__(256) void score_finalize_kernel(
    float* __restrict__ h, const float* __restrict__ agg,
    const float* __restrict__ cb, const float* __restrict__ h0,
    const int* __restrict__ batch, const float* __restrict__ gf,
    const float* __restrict__ W1, const float* __restrict__ b1,
    const float* __restrict__ W2, const float* __restrict__ b2,
    float* __restrict__ score, int N_) {
  const int lane = threadIdx.x & 63;
  const int n =
      __builtin_amdgcn_readfirstlane(blockIdx.x * 4 + (threadIdx.x >> 6));
  if (n >= N_) return;
  size_t idx = (size_t)n * 64 + lane;
  float hv = h[idx] + fmaf(agg[idx], 0.1f, cb[lane]) + h0[idx];
  h[idx] = hv;
  float acc = b1[lane];
  const float* W1l = W1 + lane;
#pragma unroll 8
  for (int k = 0; k < 64; ++k) acc = fmaf(__shfl(hv, k), W1l[k * 64], acc);
  const int bn = batch[n];  // scalar
  const float* g = gf + (size_t)bn * 108;
#pragma unroll 4
  for (int k = 0; k < 108; ++k) acc = fmaf(g[k], W1l[(64 + k) * 64], acc);
  acc = LRELU(acc);
  float v = wave_sum(acc * W2[lane]);
  if (lane == 0) score[n] = v + b2[0];
}

// ---------------------------------------------------------------------------
// Per-graph softmax-attention pool + output MLP.  One block per graph.
// Graph bounds found by binary search over sorted batch_idx (no bounds
// kernel / gstart buffer needed).
__global__ __launch_bounds__(256) void pool_out_kernel(
    const float* __restrict__ h, const float* __restrict__ score,
    const int* __restrict__ batch, int N_, const float* __restrict__ W1,
    const float* __restrict__ b1, const float* __restrict__ W2,
    const float* __restrict__ b2, float* __restrict__ out) {
  int g = blockIdx.x;
  int tid = threadIdx.x;
  __shared__ int sh_s0, sh_s1;
  __shared__ float red[256];
  __shared__ float pool[64];
  __shared__ float sh_smax, sh_denom;
  if (tid == 0) {  // lower_bound(batch, g)
    int lo = 0, hi = N_;
    while (lo < hi) {
      int mid = (lo + hi) >> 1;
      if (batch[mid] < g) lo = mid + 1; else hi = mid;
    }
    sh_s0 = lo;
  } else if (tid == 1) {  // lower_bound(batch, g+1)
    int lo = 0, hi = N_;
    while (lo < hi) {
      int mid = (lo + hi) >> 1;
      if (batch[mid] < g + 1) lo = mid + 1; else hi = mid;
    }
    sh_s1 = lo;
  }
  __syncthreads();
  int s0 = sh_s0, s1 = sh_s1;
  float lm = -1e30f;
  for (int n = s0 + tid; n < s1; n += 256) lm = fmaxf(lm, score[n]);
  red[tid] = lm;
  __syncthreads();
  for (int off = 128; off; off >>= 1) {
    if (tid < off) red[tid] = fmaxf(red[tid], red[tid + off]);
    __syncthreads();
  }
  if (tid == 0) sh_smax = red[0];
  __syncthreads();
  float smax = sh_smax;
  __syncthreads();
  float ls = 0.f;
  for (int n = s0 + tid; n < s1; n += 256) ls += __expf(score[n] - smax);
  red[tid] = ls;
  __syncthreads();
  for (int off = 128; off; off >>= 1) {
    if (tid < off) red[tid] += red[tid + off];
    __syncthreads();
  }
  if (tid == 0) sh_denom = red[0];
  __syncthreads();
  float denom = sh_denom;
  float invd = denom > 0.f ? 1.0f / denom : 0.f;
  __syncthreads();
  int f = tid & 63, sub = tid >> 6;
  float acc = 0.f;
  for (int n = s0 + sub; n < s1; n += 4)
    acc = fmaf(__expf(score[n] - smax), h[(size_t)n * 64 + f], acc);
  red[tid] = acc;
  __syncthreads();
  if (tid < 64)
    pool[tid] =
        (red[tid] + red[tid + 64] + red[tid + 128] + red[tid + 192]) * invd;
  __syncthreads();
  if (tid < 64) {
    float a = b1[tid];
#pragma unroll 8
    for (int k = 0; k < 64; ++k) a = fmaf(pool[k], W1[k * 64 + tid], a);
    a = fmaxf(a, 0.f);
    red[tid] = a * W2[tid];
  }
  __syncthreads();
  if (tid == 0) {
    float s = 0.f;
    for (int k = 0; k < 64; ++k) s += red[k];
    out[g] = s + b2[0];
  }
}

// ---------------------------------------------------------------------------
extern "C" void kernel_launch(void* const* d_in, const int* in_sizes, int n_in,
                              void* d_out, int out_size, void* d_ws,
                              size_t ws_size, hipStream_t stream) {
  const float* x          = (const float*)d_in[0];
  const int*   edge_index = (const int*)d_in[1];
  const float* edge_attr  = (const float*)d_in[2];
  const int*   batch_idx  = (const int*)d_in[3];
  const float* gf         = (const float*)d_in[4];
  const float* node_W     = (const float*)d_in[5];
  const float* node_b     = (const float*)d_in[6];
  const float* edge_W     = (const float*)d_in[7];
  const float* edge_b     = (const float*)d_in[8];
  const float* conv_W     = (const float*)d_in[9];
  const float* conv_att   = (const float*)d_in[10];
  const float* conv_b     = (const float*)d_in[11];
  const float* conv_gamma = (const float*)d_in[12];
  const float* conv_beta  = (const float*)d_in[13];
  const float* ga_W1      = (const float*)d_in[14];
  const float* ga_b1      = (const float*)d_in[15];
  const float* ga_W2      = (const float*)d_in[16];
  const float* ga_b2      = (const float*)d_in[17];
  const float* out_W1     = (const float*)d_in[18];
  const float* out_b1     = (const float*)d_in[19];
  const float* out_W2     = (const float*)d_in[20];
  const float* out_b2     = (const float*)d_in[21];
  float* out = (float*)d_out;

  const int N = in_sizes[3];        // 10000
  const int E = in_sizes[2] / 50;   // 40000
  const int G = in_sizes[4] / 108;  // 128
  const int L = 5;

  float* ws = (float*)d_ws;
  float* h    = ws;  ws += (size_t)N * 64;
  float* h0   = ws;  ws += (size_t)N * 64;
  float* ea   = ws;  ws += (size_t)E * 64;
  float* P    = ws;  ws += (size_t)N * 640;
  float* agg  = ws;  ws += (size_t)N * 64;
  float* scr  = ws;  ws += N;

  const int* row = edge_index;
  const int* col = edge_index + E;

  int nodeBlocks = (N + 3) / 4;
  int edgeBlocks = (E + 3) / 4;
  embed2_kernel<<<nodeBlocks + edgeBlocks, 256, 0, stream>>>(
      x, node_W, node_b, h0, N, edge_attr, edge_W, edge_b, ea, E, nodeBlocks);
  (void)hipMemsetAsync(agg, 0, (size_t)N * 64 * sizeof(float), stream);

  for (int i = 0; i < L; ++i) {
    const float* Wi = conv_W + (size_t)i * 128 * 640;
    if (i == 0) {
      update_gemm_kernel<<<(N / 4 + 3) / 4, 256, 0, stream>>>(
          h0, h, agg, nullptr, Wi, P, N, -1);
    } else {
      update_gemm_kernel<<<(N / 4 + 3) / 4, 256, 0, stream>>>(
          nullptr, h, agg, conv_b + (i - 1) * 64, Wi, P, N,
          (i - 1) == 0 ? 0 : 1);
    }
    int waves = (E + 7) / 8;
    edge_fused_kernel<<<(waves + 3) / 4, 256, 0, stream>>>(
        P, ea, Wi + 64 * 640, row, col, conv_att + (size_t)i * 1280,
        conv_gamma + i * 10, conv_beta + i * 10, agg, E);
  }

  score_finalize_kernel<<<(N + 3) / 4, 256, 0, stream>>>(
      h, agg, conv_b + (L - 1) * 64, h0, batch_idx, gf, ga_W1, ga_b1, ga_W2,
      ga_b2, scr, N);
  pool_out_kernel<<<G, 256, 0, stream>>>(h, scr, batch_idx, N, out_W1, out_b1,
                                         out_W2, out_b2, out);
}